// Round 11
// baseline (258.268 us; speedup 1.0000x reference)
//
#include <hip/hip_runtime.h>
#include <cstdint>

typedef short bf16x8 __attribute__((ext_vector_type(8)));
typedef float f32x4 __attribute__((ext_vector_type(4)));
#define MFMA16(a, b, c) __builtin_amdgcn_mfma_f32_16x16x32_bf16((a), (b), (c), 0, 0, 0)

static __device__ __forceinline__ float fastrcp(float x) {
  float r;
  asm("v_rcp_f32 %0, %1" : "=v"(r) : "v"(x));
  return r;
}
static __device__ __forceinline__ float fastexp2(float x) {
  float r;
  asm("v_exp_f32 %0, %1" : "=v"(r) : "v"(x));
  return r;
}
static __device__ __forceinline__ float silu_(float x) {
  return x * fastrcp(1.f + __expf(-x));
}
static __device__ __forceinline__ unsigned short f2bf(float f) {
  union { float f; unsigned u; } v; v.f = f;
  unsigned r = v.u + 0x7FFF + ((v.u >> 16) & 1);
  return (unsigned short)(r >> 16);
}
static __device__ __forceinline__ void bf2x(unsigned p, float& lo, float& hi) {
  union { unsigned u; float f; } a, bb;
  a.u = p << 16; bb.u = p & 0xffff0000u;
  lo = a.f; hi = bb.f;
}
static __device__ __forceinline__ float bflo(unsigned short h) {
  union { unsigned u; float f; } a;
  a.u = ((unsigned)h) << 16;
  return a.f;
}

// ---------------- K1: FUSED front: proj-MFMA blocks (0..511) || prep blocks (512..815) ---
__global__ __launch_bounds__(256, 4) void k_front(
    const float* __restrict__ x, const float* __restrict__ pw,
    const float* __restrict__ pb,
    const float* __restrict__ g0, const float* __restrict__ be0,
    const float* __restrict__ mm0, const float* __restrict__ vv0,
    const float* __restrict__ c1_w, const float* __restrict__ c2_w,
    const float* __restrict__ fc_w, const float* __restrict__ opw,
    const float* __restrict__ in_w, const float* __restrict__ xp_w,
    unsigned short* __restrict__ p_bf,
    unsigned short* __restrict__ Wf1, unsigned short* __restrict__ Wf2,
    unsigned short* __restrict__ Wfin, unsigned short* __restrict__ Wfxp,
    float* __restrict__ W2, float* __restrict__ cnn_sum)
{
  __shared__ __align__(16) char fsm[55296];
  int tid = threadIdx.x;
  if (blockIdx.x >= 512) {    // ---- prep branch ----
    int i = (blockIdx.x - 512) * 256 + tid;
    if (i < 36864) {           // Wf2[t][cf 0..7][lane][j]
      int j = i & 7, l = (i >> 3) & 63, m = (i >> 9) & 7, t = i >> 12;
      int co = m * 16 + (l & 15), ci = ((l >> 4) << 3) + j;
      Wf2[i] = f2bf(c2_w[(size_t)(co * 32 + ci) * 9 + t]);
    } else if (i < 46080) {    // Wf1
      int ii = i - 36864;
      int j = ii & 7, l = (ii >> 3) & 63, m = (ii >> 9) & 1, t = ii >> 10;
      int co = m * 16 + (l & 15), ci = ((l >> 4) << 3) + j;
      Wf1[ii] = f2bf(c1_w[(size_t)(co * 32 + ci) * 9 + t]);
    } else if (i < 54272) {    // W2 = fc_w @ out_proj_w
      int ii = i - 46080;
      int f = ii >> 6, d2 = ii & 63;
      float a = 0.f;
      #pragma unroll
      for (int dm = 0; dm < 32; dm++) a = fmaf(fc_w[(f << 5) + dm], opw[(dm << 6) + d2], a);
      W2[ii] = a;
    } else if (i < 70656) {
      cnn_sum[i - 54272] = 0.f;
    } else if (i < 74752) {    // Wfin
      int ii = i - 70656;
      int j = ii & 7, l = (ii >> 3) & 63, ot = ii >> 9;
      int o = (ot << 4) + (l & 15), c = ((l >> 4) << 3) + j;
      Wfin[ii] = f2bf(in_w[(o << 5) + c]);
    } else if (i < 77824) {    // Wfxp
      int ii = i - 74752;
      int j = ii & 7, l = (ii >> 3) & 63, kh = (ii >> 9) & 1, ot = ii >> 10;
      int jr = (ot << 4) + (l & 15), c = (kh << 5) + ((l >> 4) << 3) + j;
      Wfxp[ii] = (jr < 34) ? f2bf(xp_w[(jr << 6) + c]) : (unsigned short)0;
    }
    return;
  }
  // ---- proj branch ----
  unsigned* xT = (unsigned*)fsm;                            // [2][256*20]
  unsigned short* WfpL = (unsigned short*)(fsm + 40960);    // 7168
  int b = blockIdx.x >> 2, l0 = (blockIdx.x & 3) << 8;
  int lane = tid & 63, w = tid >> 6;
  int li = lane & 15, kg4 = (lane >> 4) << 2;
  for (int i = tid; i < 7168; i += 256) {   // build Wfp fragment table in LDS
    int j = i & 7, l = (i >> 3) & 63, m = (i >> 9) & 1, kt = i >> 10;
    int co = (m << 4) + (l & 15), c = (kt << 5) + ((l >> 4) << 3) + j;
    WfpL[i] = (c < 200) ? f2bf(pw[co * 200 + c]) : (unsigned short)0;
  }
  float scv[2][4], sbv[2][4];
  #pragma unroll
  for (int m = 0; m < 2; m++)
    #pragma unroll
    for (int jj = 0; jj < 4; jj++) {
      int co = m * 16 + ((lane >> 4) << 2) + jj;
      float s = g0[co] * rsqrtf(vv0[co] + 1e-5f);
      scv[m][jj] = s;
      sbv[m][jj] = fmaf(pb[co] - mm0[co], s, be0[co]);
    }
  const float* xb = x + (size_t)b * 200 * 1024 + l0 + tid;
  #pragma unroll
  for (int p = 0; p < 16; p++) {     // chunk 0 (c = 0..31, all valid)
    float v0 = xb[(2 * p) << 10];
    float v1 = xb[(2 * p + 1) << 10];
    xT[tid * 20 + p] = (unsigned)f2bf(v0) | ((unsigned)f2bf(v1) << 16);
  }
  __syncthreads();
  f32x4 acc[4][2];
  #pragma unroll
  for (int q = 0; q < 4; q++) {
    acc[q][0] = (f32x4){0.f, 0.f, 0.f, 0.f};
    acc[q][1] = (f32x4){0.f, 0.f, 0.f, 0.f};
  }
  int buf = 0;
  for (int kt = 0; kt < 7; kt++) {
    if (kt < 6) {                    // stage next chunk while MFMA on current
      const float* xc = xb + (((size_t)(kt + 1)) << 15);
      int cb = (kt + 1) * 32;
      #pragma unroll
      for (int p = 0; p < 16; p++) {
        int c = cb + 2 * p;
        float v0 = (c < 200) ? xc[(2 * p) << 10] : 0.f;
        float v1 = (c + 1 < 200) ? xc[(2 * p + 1) << 10] : 0.f;
        xT[(buf ^ 1) * 5120 + tid * 20 + p] = (unsigned)f2bf(v0) | ((unsigned)f2bf(v1) << 16);
      }
    }
    bf16x8 a0 = *reinterpret_cast<const bf16x8*>(&WfpL[(((kt << 1) + 0) * 64 + lane) << 3]);
    bf16x8 a1 = *reinterpret_cast<const bf16x8*>(&WfpL[(((kt << 1) + 1) * 64 + lane) << 3]);
    #pragma unroll
    for (int q = 0; q < 4; q++) {
      int px = ((w + (q << 2)) << 4) + li;
      bf16x8 bfr = *reinterpret_cast<const bf16x8*>(&xT[buf * 5120 + px * 20 + kg4]);
      acc[q][0] = MFMA16(a0, bfr, acc[q][0]);
      acc[q][1] = MFMA16(a1, bfr, acc[q][1]);
    }
    __syncthreads();
    buf ^= 1;
  }
  #pragma unroll
  for (int q = 0; q < 4; q++) {
    int px = ((w + (q << 2)) << 4) + li;
    size_t obase = (((size_t)b << 10) + l0 + px) << 5;
    #pragma unroll
    for (int m = 0; m < 2; m++) {
      f32x4 av = acc[q][m];
      ushort4 pk;
      pk.x = f2bf(fmaxf(fmaf(av[0], scv[m][0], sbv[m][0]), 0.f));
      pk.y = f2bf(fmaxf(fmaf(av[1], scv[m][1], sbv[m][1]), 0.f));
      pk.z = f2bf(fmaxf(fmaf(av[2], scv[m][2], sbv[m][2]), 0.f));
      pk.w = f2bf(fmaxf(fmaf(av[3], scv[m][3], sbv[m][3]), 0.f));
      *reinterpret_cast<ushort4*>(&p_bf[obase + m * 16 + ((lane >> 4) << 2)]) = pk;
    }
  }
}

// ---------------- K2: conv1 waves (blocks 0..159, LDS/barrier-free) || chunk-parallel
// mamba blocks (160..2207): phases + intra-chunk scan -> (P,q,R,S) ----------------------
__global__ __launch_bounds__(1024, 8) void k_mamba(
    const unsigned short* __restrict__ p_bf,
    const unsigned short* __restrict__ Wfin,
    const unsigned short* __restrict__ Wfxp,
    const float* __restrict__ conv_w,    // (64,4)
    const float* __restrict__ conv_b,    // (64)
    const float* __restrict__ dt_w,      // (64,2)
    const float* __restrict__ dt_b,      // (64)
    const float* __restrict__ A_log,     // (64,16)
    const unsigned short* __restrict__ Wf1,
    const float* __restrict__ c1bias,
    const float* __restrict__ g1, const float* __restrict__ be1,
    const float* __restrict__ mm1, const float* __restrict__ vv1,
    unsigned short* __restrict__ c1_bf,
    float* __restrict__ pqrs,            // (128,16,64,16,4)
    float* __restrict__ au_g)            // (128,16,64)
{
  __shared__ __align__(16) char smem[65072];
  int tid = threadIdx.x, lane = tid & 63, w = tid >> 6;
  int li = lane & 15, cig8 = (lane >> 4) << 3;

  if (blockIdx.x < 160) {   // ---- conv1 branch: 16 independent waves, no LDS/barriers ----
    int j = blockIdx.x * 16 + w;        // 0..2559
    int ob = j >> 2, ow = j & 3;
    int b1 = ob / 5, s1 = ob % 5;
    int y0 = s1 * 6;
    float scv[2][4], sbv[2][4];
    #pragma unroll
    for (int m = 0; m < 2; m++)
      #pragma unroll
      for (int jj = 0; jj < 4; jj++) {
        int co = m * 16 + ((lane >> 4) << 2) + jj;
        float sc = g1[co] * rsqrtf(vv1[co] + 1e-5f);
        scv[m][jj] = sc;
        sbv[m][jj] = fmaf(c1bias[co] - mm1[co], sc, be1[co]);
      }
    #pragma unroll
    for (int q = 0; q < 3; q++) {
      int pf = ow + (q << 2);
      int p = pf * 16 + li;
      int pv = (p < 180) ? p : 0;
      int ry = pv / 30, rx = pv % 30;
      f32x4 a0 = {0.f, 0.f, 0.f, 0.f}, a1 = {0.f, 0.f, 0.f, 0.f};
      #pragma unroll
      for (int t = 0; t < 9; t++) {
        int dy = t / 3, dx = t % 3;
        bf16x8 bfr = *reinterpret_cast<const bf16x8*>(
            &p_bf[((((size_t)b1 << 10) + (y0 + ry + dy) * 32 + rx + dx) << 5) + cig8]);
        bf16x8 w0 = *reinterpret_cast<const bf16x8*>(&Wf1[(((t << 1) + 0) * 64 + lane) << 3]);
        bf16x8 w1 = *reinterpret_cast<const bf16x8*>(&Wf1[(((t << 1) + 1) * 64 + lane) << 3]);
        a0 = MFMA16(w0, bfr, a0);
        a1 = MFMA16(w1, bfr, a1);
      }
      if (p < 180) {
        size_t obase = ((size_t)b1 * 900 + (size_t)(y0 + ry) * 30 + rx) << 5;
        #pragma unroll
        for (int m = 0; m < 2; m++) {
          f32x4 av = m ? a1 : a0;
          ushort4 pk;
          pk.x = f2bf(fmaxf(fmaf(av[0], scv[m][0], sbv[m][0]), 0.f));
          pk.y = f2bf(fmaxf(fmaf(av[1], scv[m][1], sbv[m][1]), 0.f));
          pk.z = f2bf(fmaxf(fmaf(av[2], scv[m][2], sbv[m][2]), 0.f));
          pk.w = f2bf(fmaxf(fmaf(av[3], scv[m][3], sbv[m][3]), 0.f));
          *reinterpret_cast<ushort4*>(&c1_bf[obase + m * 16 + ((lane >> 4) << 2)]) = pk;
        }
      }
    }
    return;
  }

  // ---- mamba branch ----
  float* xm  = (float*)smem;                               // [67][68] f32 (xz rows; r=t+3)
  float* dlS = (float*)smem;                               // [64][68] alias (phase4+)
  unsigned short* ubS  = (unsigned short*)(smem + 18224);  // [64][72] bf16 u, t-major
  unsigned short* uTb  = (unsigned short*)(smem + 27440);  // [64][72] bf16 u, d-major
  unsigned short* duzP = (unsigned short*)(smem + 36656);  // [64][17][8] {du0..3, z0..3}
  float* bcT  = (float*)(smem + 54064);                    // [32][68]; cols 64..67 = dt01
  float* cwS  = (float*)(smem + 62768);                    // [64][4]
  float* cbS  = (float*)(smem + 63792);                    // [64]
  float* dtwS = (float*)(smem + 64048);                    // [64][2]
  float* dtbS = (float*)(smem + 64560);                    // [64]
  float* auS  = (float*)(smem + 64816);                    // [64]

  int bm = blockIdx.x - 160;
  int b = bm >> 4, ch = bm & 15;

  if (tid < 256) cwS[tid] = conv_w[tid];
  else if (tid < 320) cbS[tid - 256] = conv_b[tid - 256];
  else if (tid < 448) dtwS[tid - 320] = dt_w[tid - 320];
  else if (tid < 512) dtbS[tid - 448] = dt_b[tid - 448];
  else if (tid < 576) auS[tid - 512] = 0.f;

  const unsigned short* pbf_b = p_bf + ((size_t)b << 15);

  // ---- phase1 (MFMA): xz = in_w @ tok ; x (rows -3..63) -> xm ; silu(z) -> duzP z-half --
  for (int j = w; j < 36; j += 16) {
    if (j < 20) {
      int ot = j / 5, tt = j % 5;
      int r = tt * 16 + li;
      int tg = (ch << 6) + r - 3;
      bf16x8 bfr = {0,0,0,0,0,0,0,0};
      if (r < 67 && tg >= 0)
        bfr = *reinterpret_cast<const bf16x8*>(pbf_b + ((size_t)tg << 5) + cig8);
      bf16x8 aW = *reinterpret_cast<const bf16x8*>(&Wfin[((ot << 6) + lane) << 3]);
      f32x4 acc = {0.f, 0.f, 0.f, 0.f};
      acc = MFMA16(aW, bfr, acc);
      if (r < 67)
        *reinterpret_cast<float4*>(&xm[r * 68 + (ot << 4) + ((lane >> 4) << 2)]) =
            make_float4(acc[0], acc[1], acc[2], acc[3]);
    } else {
      int jz = j - 20;
      int zot = jz >> 2, tt = jz & 3;
      int t = tt * 16 + li;
      int tg = (ch << 6) + t;
      bf16x8 bfr = *reinterpret_cast<const bf16x8*>(pbf_b + ((size_t)tg << 5) + cig8);
      bf16x8 aW = *reinterpret_cast<const bf16x8*>(&Wfin[(((4 + zot) << 6) + lane) << 3]);
      f32x4 acc = {0.f, 0.f, 0.f, 0.f};
      acc = MFMA16(aW, bfr, acc);
      int dzb = (zot << 4) + ((lane >> 4) << 2);
      int toff = ((t >> 2) << 3) + 4 + (t & 3);
      #pragma unroll
      for (int q = 0; q < 4; q++)
        duzP[(dzb + q) * 136 + toff] = f2bf(silu_(acc[q]));
    }
  }
  __syncthreads();                        // B: xm, z, weights ready
  // ---- phase2: causal dwconv(4) + silu -> ubS, uTb ; au partial -> auS -----------------
  {
    int d2 = tid & 63, oct = tid >> 6;
    int t0 = oct << 2;
    float4 cw4 = *reinterpret_cast<const float4*>(&cwS[d2 << 2]);
    float cb1 = cbS[d2];
    float x0 = xm[t0 * 68 + d2], x1 = xm[(t0 + 1) * 68 + d2], x2 = xm[(t0 + 2) * 68 + d2];
    uint2 zz2 = *reinterpret_cast<const uint2*>(&duzP[d2 * 136 + (oct << 3) + 4]);
    float zf[4];
    bf2x(zz2.x, zf[0], zf[1]); bf2x(zz2.y, zf[2], zf[3]);
    unsigned short up[4];
    float aup = 0.f;
    #pragma unroll
    for (int s = 0; s < 4; s++) {
      int t = t0 + s;
      float x3 = xm[(t + 3) * 68 + d2];
      float a = cb1;
      a = fmaf(cw4.x, x0, a); a = fmaf(cw4.y, x1, a);
      a = fmaf(cw4.z, x2, a); a = fmaf(cw4.w, x3, a);
      float uu = silu_(a);
      unsigned short ub_ = f2bf(uu);
      ubS[t * 72 + d2] = ub_;
      up[s] = ub_;
      aup = fmaf(uu, zf[s], aup);
      x0 = x1; x1 = x2; x2 = x3;
    }
    uint2 pk;
    pk.x = (unsigned)up[0] | ((unsigned)up[1] << 16);
    pk.y = (unsigned)up[2] | ((unsigned)up[3] << 16);
    *reinterpret_cast<uint2*>(&uTb[d2 * 72 + t0]) = pk;
    atomicAdd(&auS[d2], aup);
  }
  __syncthreads();                        // C: u ready
  // ---- phase3 (MFMA): xdbl = xp_w @ u ; dt -> bcT pad, B/C -> bcT ----------------------
  if (w < 12) {
    int ot = w >> 2, tt = w & 3;
    int t = tt * 16 + li;
    const unsigned short* ub = &ubS[t * 72];
    bf16x8 b0 = *reinterpret_cast<const bf16x8*>(ub + cig8);
    bf16x8 b1 = *reinterpret_cast<const bf16x8*>(ub + 32 + cig8);
    bf16x8 a0 = *reinterpret_cast<const bf16x8*>(&Wfxp[(((ot << 1) + 0) * 64 + lane) << 3]);
    bf16x8 a1 = *reinterpret_cast<const bf16x8*>(&Wfxp[(((ot << 1) + 1) * 64 + lane) << 3]);
    f32x4 acc = {0.f, 0.f, 0.f, 0.f};
    acc = MFMA16(a0, b0, acc);
    acc = MFMA16(a1, b1, acc);
    int jb = (ot << 4) + ((lane >> 4) << 2);
    #pragma unroll
    for (int q = 0; q < 4; q++) {
      int jj = jb + q;
      if (jj < 2) bcT[(t & 31) * 68 + 64 + (jj << 1) + (t >> 5)] = acc[q];
      else if (jj < 34) bcT[(jj - 2) * 68 + t] = acc[q];
    }
  }
  __syncthreads();                        // D: bcT (incl dt01) ready
  // ---- phase4: delta = softplus(..) -> dlS ; du = delta*u -> duzP du-half --------------
  // lane->dg mapping stride-1 (l15 + 16q) => 2-way banks (was stride-4 => 8-way)
  {
    int t = tid >> 4, l15 = tid & 15;
    int tr = t & 31, th = t >> 5;
    float d0 = bcT[tr * 68 + 64 + th];
    float d1 = bcT[tr * 68 + 66 + th];
    int toff = ((t >> 2) << 3) + (t & 3);
    #pragma unroll
    for (int q = 0; q < 4; q++) {
      int dg = l15 + (q << 4);
      float pre = fmaf(d0, dtwS[dg << 1], fmaf(d1, dtwS[(dg << 1) + 1], dtbS[dg]));
      float dl_ = (pre > 20.f) ? pre : __logf(1.f + __expf(pre));
      dlS[dg * 68 + t] = dl_;
      float uf = bflo(uTb[dg * 72 + t]);
      duzP[dg * 136 + toff] = f2bf(dl_ * uf);
    }
  }
  __syncthreads();                        // E: dlS, duzP ready
  // ---- intra-chunk scan: h_out = P h_in + q ; y = R h_in + S ---------------------------
  {
    int sd = tid >> 4, sn = tid & 15;
    float Areg2 = -__expf(A_log[(sd << 4) + sn]) * 1.44269504f;
    float P = 1.f, qq = 0.f, R = 0.f, S = 0.f;
    const float* dr = &dlS[sd * 68];
    const unsigned short* dz = &duzP[sd * 136];
    const float* Br = &bcT[sn * 68];
    const float* Cr = &bcT[(16 + sn) * 68];
    for (int g = 0; g < 16; g++) {
      float4 dv = *reinterpret_cast<const float4*>(dr + (g << 2));
      uint4 duz = *reinterpret_cast<const uint4*>(dz + (g << 3));
      float4 Bv = *reinterpret_cast<const float4*>(Br + (g << 2));
      float4 Cv = *reinterpret_cast<const float4*>(Cr + (g << 2));
      float du0, du1, du2, du3, z0, z1, z2, z3;
      bf2x(duz.x, du0, du1); bf2x(duz.y, du2, du3);
      bf2x(duz.z, z0, z1);  bf2x(duz.w, z2, z3);
      float e0 = fastexp2(dv.x * Areg2), e1 = fastexp2(dv.y * Areg2);
      float e2 = fastexp2(dv.z * Areg2), e3 = fastexp2(dv.w * Areg2);
      float c0 = Cv.x * z0, c1 = Cv.y * z1, c2 = Cv.z * z2, c3 = Cv.w * z3;
      P = e0 * P; qq = fmaf(e0, qq, du0 * Bv.x); R = fmaf(c0, P, R); S = fmaf(c0, qq, S);
      P = e1 * P; qq = fmaf(e1, qq, du1 * Bv.y); R = fmaf(c1, P, R); S = fmaf(c1, qq, S);
      P = e2 * P; qq = fmaf(e2, qq, du2 * Bv.z); R = fmaf(c2, P, R); S = fmaf(c2, qq, S);
      P = e3 * P; qq = fmaf(e3, qq, du3 * Bv.w); R = fmaf(c3, P, R); S = fmaf(c3, qq, S);
    }
    size_t idx = ((((size_t)b << 4) + ch) << 10) + (sd << 4) + sn;
    *reinterpret_cast<float4*>(pqrs + (idx << 2)) = make_float4(P, qq, R, S);
    if (sn == 0) au_g[((((size_t)b << 4) + ch) << 6) + sd] = auS[sd];
  }
}

// ---------------- K3: FUSED back: conv2 wave-jobs (blocks 0..223, LDS-free) ||
// comb blocks (224..351) ----------------------------------------------------------------
__global__ __launch_bounds__(1024, 8) void k_back(
    const unsigned short* __restrict__ c1_bf, const unsigned short* __restrict__ Wf2,
    const float* __restrict__ cb2,
    const float* __restrict__ g, const float* __restrict__ be,
    const float* __restrict__ mm, const float* __restrict__ vv,
    const float* __restrict__ pqrs, const float* __restrict__ au_g,
    const float* __restrict__ Dp,
    float* __restrict__ cnn_sum, float* __restrict__ ybar)
{
  int tid = threadIdx.x, lane = tid & 63, w = tid >> 6;
  int li = lane & 15, cig8 = (lane >> 4) << 3;
  if (blockIdx.x >= 224) {    // ---- comb branch: block = b; 1024 thr = (64 d)x(16 n) ----
    int b = blockIdx.x - 224;
    int sd = tid >> 4, sn = tid & 15;
    float h = 0.f, y = 0.f;
    for (int half = 0; half < 2; half++) {
      float4 pq[8];
      #pragma unroll
      for (int c = 0; c < 8; c++) {
        size_t idx = ((((size_t)b << 4) + (half << 3) + c) << 10) + (sd << 4) + sn;
        pq[c] = *reinterpret_cast<const float4*>(pqrs + (idx << 2));
      }
      #pragma unroll
      for (int c = 0; c < 8; c++) {
        y = fmaf(pq[c].z, h, y + pq[c].w);
        h = fmaf(pq[c].x, h, pq[c].y);
      }
    }
    float val = y + Dp[sd] * au_g[((((size_t)b << 4) + sn) << 6) + sd];
    val += __shfl_xor(val, 1); val += __shfl_xor(val, 2);
    val += __shfl_xor(val, 4); val += __shfl_xor(val, 8);
    if (sn == 0) ybar[(b << 6) + sd] = val * (1.f / 1024.f);
    return;
  }
  // ---- conv2 branch: wave job, no LDS/barriers ----
  int j = blockIdx.x * 16 + w;          // 0..3583
  int ob = j >> 2, ow = j & 3;
  int b = ob / 7, s = ob % 7;
  int y0 = s * 4;
  float scv[2][4], sbv[2][4];
  float psum[2][4] = {{0.f,0.f,0.f,0.f},{0.f,0.f,0.f,0.f}};
  #pragma unroll
  for (int m = 0; m < 2; m++)
    #pragma unroll
    for (int jj = 0; jj < 4; jj++) {
      int co = (ow << 5) + m * 16 + ((lane >> 4) << 2) + jj;
      float sc = g[co] * rsqrtf(vv[co] + 1e-5f);
      scv[m][jj] = sc;
      sbv[m][jj] = fmaf(cb2[co] - mm[co], sc, be[co]);
    }
  #pragma unroll
  for (int pf = 0; pf < 7; pf++) {
    int p = pf * 16 + li;
    int ry = p / 28, rx = p % 28;
    f32x4 a0 = {0.f, 0.f, 0.f, 0.f}, a1 = {0.f, 0.f, 0.f, 0.f};
    #pragma unroll
    for (int t = 0; t < 9; t++) {
      int dy = t / 3, dx = t % 3;
      bf16x8 bfr = *reinterpret_cast<const bf16x8*>(
          &c1_bf[(((size_t)b * 900 + (size_t)(y0 + ry + dy) * 30 + rx + dx) << 5) + cig8]);
      bf16x8 w0 = *reinterpret_cast<const bf16x8*>(&Wf2[(((t << 3) + (ow << 1) + 0) * 64 + lane) << 3]);
      bf16x8 w1 = *reinterpret_cast<const bf16x8*>(&Wf2[(((t << 3) + (ow << 1) + 1) * 64 + lane) << 3]);
      a0 = MFMA16(w0, bfr, a0);
      a1 = MFMA16(w1, bfr, a1);
    }
    #pragma unroll
    for (int jj = 0; jj < 4; jj++) {
      psum[0][jj] += fmaxf(fmaf(a0[jj], scv[0][jj], sbv[0][jj]), 0.f);
      psum[1][jj] += fmaxf(fmaf(a1[jj], scv[1][jj], sbv[1][jj]), 0.f);
    }
  }
  #pragma unroll
  for (int m = 0; m < 2; m++)
    #pragma unroll
    for (int jj = 0; jj < 4; jj++) {
      float v = psum[m][jj];
      v += __shfl_xor(v, 1); v += __shfl_xor(v, 2);
      v += __shfl_xor(v, 4); v += __shfl_xor(v, 8);
      if (li == 0) {
        int co = (ow << 5) + m * 16 + ((lane >> 4) << 2) + jj;
        atomicAdd(&cnn_sum[((size_t)b << 7) + co], v);
      }
    }
}

// ---------------- K4: out = ybar @ W2^T + fc_b + cnn_sum/784 ----------------
__global__ __launch_bounds__(256) void k_final(
    const float* __restrict__ ybar, const float* __restrict__ W2,
    const float* __restrict__ fc_b, const float* __restrict__ cnn_sum,
    float* __restrict__ out)
{
  int i = blockIdx.x * 256 + threadIdx.x;   // 16384
  int b = i >> 7, f = i & 127;
  float a = 0.f;
  #pragma unroll
  for (int d2 = 0; d2 < 64; d2++) a = fmaf(ybar[(b << 6) + d2], W2[(f << 6) + d2], a);
  out[i] = a + fc_b[f] + cnn_sum[i] * (1.f / 784.f);
}

extern "C" void kernel_launch(void* const* d_in, const int* in_sizes, int n_in,
                              void* d_out, int out_size, void* d_ws, size_t ws_size,
                              hipStream_t stream) {
  (void)in_sizes; (void)n_in; (void)out_size; (void)ws_size;
  const float* x         = (const float*)d_in[0];
  const float* proj_w    = (const float*)d_in[1];
  const float* proj_b    = (const float*)d_in[2];
  const float* bn0_g     = (const float*)d_in[3];
  const float* bn0_b     = (const float*)d_in[4];
  const float* bn0_m     = (const float*)d_in[5];
  const float* bn0_v     = (const float*)d_in[6];
  const float* in_proj_w = (const float*)d_in[7];
  const float* conv_w    = (const float*)d_in[8];
  const float* conv_b    = (const float*)d_in[9];
  const float* x_proj_w  = (const float*)d_in[10];
  const float* dt_w      = (const float*)d_in[11];
  const float* dt_b      = (const float*)d_in[12];
  const float* A_log     = (const float*)d_in[13];
  const float* Dp        = (const float*)d_in[14];
  const float* out_proj_w= (const float*)d_in[15];
  const float* fc_w      = (const float*)d_in[16];
  const float* fc_b      = (const float*)d_in[17];
  const float* c1_w      = (const float*)d_in[18];
  const float* c1_b      = (const float*)d_in[19];
  const float* bn1_g     = (const float*)d_in[20];
  const float* bn1_b     = (const float*)d_in[21];
  const float* bn1_m     = (const float*)d_in[22];
  const float* bn1_v     = (const float*)d_in[23];
  const float* c2_w      = (const float*)d_in[24];
  const float* c2_b      = (const float*)d_in[25];
  const float* bn2_g     = (const float*)d_in[26];
  const float* bn2_b     = (const float*)d_in[27];
  const float* bn2_m     = (const float*)d_in[28];
  const float* bn2_v     = (const float*)d_in[29];
  float* out = (float*)d_out;
  float* ws  = (float*)d_ws;
  // workspace layout (float slots); ~50 MB
  float* ybar    = ws;                                        // 8192
  float* cnn_sum = ws + 8192;                                 // 16384
  float* W2      = ws + 24576;                                // 8192
  float* pqrs    = ws + 32768;                                // 8388608
  float* au_g    = ws + 8421376;                              // 131072
  unsigned short* p_bf  = (unsigned short*)(ws + 8552448);    // 4194304 bf16
  unsigned short* c1_bf = (unsigned short*)(ws + 10649600);   // 3686400 bf16
  unsigned short* Wf1   = (unsigned short*)(ws + 12492800);   // 9216 bf16
  unsigned short* Wf2   = (unsigned short*)(ws + 12497408);   // 36864 bf16
  unsigned short* Wfin  = (unsigned short*)(ws + 12515840);   // 4096 bf16
  unsigned short* Wfxp  = (unsigned short*)(ws + 12517888);   // 3072 bf16

  k_front<<<dim3(816), dim3(256), 0, stream>>>(x, proj_w, proj_b, bn0_g, bn0_b, bn0_m, bn0_v,
                                               c1_w, c2_w, fc_w, out_proj_w, in_proj_w, x_proj_w,
                                               p_bf, Wf1, Wf2, Wfin, Wfxp, W2, cnn_sum);
  k_mamba<<<dim3(2208), dim3(1024), 0, stream>>>(p_bf, Wfin, Wfxp, conv_w, conv_b, dt_w, dt_b,
                                                 A_log, Wf1, c1_b, bn1_g, bn1_b, bn1_m, bn1_v,
                                                 c1_bf, pqrs, au_g);
  k_back<<<dim3(352), dim3(1024), 0, stream>>>(c1_bf, Wf2, c2_b, bn2_g, bn2_b, bn2_m, bn2_v,
                                               pqrs, au_g, Dp, cnn_sum, ybar);
  k_final<<<dim3(64), dim3(256), 0, stream>>>(ybar, W2, fc_b, cnn_sum, out);
}

// Round 12
// 120.736 us; speedup vs baseline: 2.1391x; 2.1391x over previous
//
#include <hip/hip_runtime.h>
#include <cstdint>

typedef short bf16x8 __attribute__((ext_vector_type(8)));
typedef float f32x4 __attribute__((ext_vector_type(4)));
#define MFMA16(a, b, c) __builtin_amdgcn_mfma_f32_16x16x32_bf16((a), (b), (c), 0, 0, 0)

static __device__ __forceinline__ float fastrcp(float x) {
  float r;
  asm("v_rcp_f32 %0, %1" : "=v"(r) : "v"(x));
  return r;
}
static __device__ __forceinline__ float fastexp2(float x) {
  float r;
  asm("v_exp_f32 %0, %1" : "=v"(r) : "v"(x));
  return r;
}
static __device__ __forceinline__ float silu_(float x) {
  return x * fastrcp(1.f + __expf(-x));
}
static __device__ __forceinline__ unsigned short f2bf(float f) {
  union { float f; unsigned u; } v; v.f = f;
  unsigned r = v.u + 0x7FFF + ((v.u >> 16) & 1);
  return (unsigned short)(r >> 16);
}
static __device__ __forceinline__ void bf2x(unsigned p, float& lo, float& hi) {
  union { unsigned u; float f; } a, bb;
  a.u = p << 16; bb.u = p & 0xffff0000u;
  lo = a.f; hi = bb.f;
}
static __device__ __forceinline__ float bflo(unsigned short h) {
  union { unsigned u; float f; } a;
  a.u = ((unsigned)h) << 16;
  return a.f;
}

// ---------------- K1: FUSED front: proj-MFMA blocks (0..511) || prep blocks (512..815) ---
__global__ __launch_bounds__(256, 4) void k_front(
    const float* __restrict__ x, const float* __restrict__ pw,
    const float* __restrict__ pb,
    const float* __restrict__ g0, const float* __restrict__ be0,
    const float* __restrict__ mm0, const float* __restrict__ vv0,
    const float* __restrict__ c1_w, const float* __restrict__ c2_w,
    const float* __restrict__ fc_w, const float* __restrict__ opw,
    const float* __restrict__ in_w, const float* __restrict__ xp_w,
    unsigned short* __restrict__ p_bf,
    unsigned short* __restrict__ Wf1, unsigned short* __restrict__ Wf2,
    unsigned short* __restrict__ Wfin, unsigned short* __restrict__ Wfxp,
    float* __restrict__ W2, float* __restrict__ cnn_sum)
{
  __shared__ __align__(16) char fsm[55296];
  int tid = threadIdx.x;
  if (blockIdx.x >= 512) {    // ---- prep branch ----
    int i = (blockIdx.x - 512) * 256 + tid;
    if (i < 36864) {           // Wf2[t][cf 0..7][lane][j]
      int j = i & 7, l = (i >> 3) & 63, m = (i >> 9) & 7, t = i >> 12;
      int co = m * 16 + (l & 15), ci = ((l >> 4) << 3) + j;
      Wf2[i] = f2bf(c2_w[(size_t)(co * 32 + ci) * 9 + t]);
    } else if (i < 46080) {    // Wf1
      int ii = i - 36864;
      int j = ii & 7, l = (ii >> 3) & 63, m = (ii >> 9) & 1, t = ii >> 10;
      int co = m * 16 + (l & 15), ci = ((l >> 4) << 3) + j;
      Wf1[ii] = f2bf(c1_w[(size_t)(co * 32 + ci) * 9 + t]);
    } else if (i < 54272) {    // W2 = fc_w @ out_proj_w
      int ii = i - 46080;
      int f = ii >> 6, d2 = ii & 63;
      float a = 0.f;
      #pragma unroll
      for (int dm = 0; dm < 32; dm++) a = fmaf(fc_w[(f << 5) + dm], opw[(dm << 6) + d2], a);
      W2[ii] = a;
    } else if (i < 70656) {
      cnn_sum[i - 54272] = 0.f;
    } else if (i < 74752) {    // Wfin
      int ii = i - 70656;
      int j = ii & 7, l = (ii >> 3) & 63, ot = ii >> 9;
      int o = (ot << 4) + (l & 15), c = ((l >> 4) << 3) + j;
      Wfin[ii] = f2bf(in_w[(o << 5) + c]);
    } else if (i < 77824) {    // Wfxp
      int ii = i - 74752;
      int j = ii & 7, l = (ii >> 3) & 63, kh = (ii >> 9) & 1, ot = ii >> 10;
      int jr = (ot << 4) + (l & 15), c = (kh << 5) + ((l >> 4) << 3) + j;
      Wfxp[ii] = (jr < 34) ? f2bf(xp_w[(jr << 6) + c]) : (unsigned short)0;
    }
    return;
  }
  // ---- proj branch ----
  unsigned* xT = (unsigned*)fsm;                            // [2][256*20]
  unsigned short* WfpL = (unsigned short*)(fsm + 40960);    // 7168
  int b = blockIdx.x >> 2, l0 = (blockIdx.x & 3) << 8;
  int lane = tid & 63, w = tid >> 6;
  int li = lane & 15, kg4 = (lane >> 4) << 2;
  for (int i = tid; i < 7168; i += 256) {   // build Wfp fragment table in LDS
    int j = i & 7, l = (i >> 3) & 63, m = (i >> 9) & 1, kt = i >> 10;
    int co = (m << 4) + (l & 15), c = (kt << 5) + ((l >> 4) << 3) + j;
    WfpL[i] = (c < 200) ? f2bf(pw[co * 200 + c]) : (unsigned short)0;
  }
  float scv[2][4], sbv[2][4];
  #pragma unroll
  for (int m = 0; m < 2; m++)
    #pragma unroll
    for (int jj = 0; jj < 4; jj++) {
      int co = m * 16 + ((lane >> 4) << 2) + jj;
      float s = g0[co] * rsqrtf(vv0[co] + 1e-5f);
      scv[m][jj] = s;
      sbv[m][jj] = fmaf(pb[co] - mm0[co], s, be0[co]);
    }
  const float* xb = x + (size_t)b * 200 * 1024 + l0 + tid;
  #pragma unroll
  for (int p = 0; p < 16; p++) {     // chunk 0 (c = 0..31, all valid)
    float v0 = xb[(2 * p) << 10];
    float v1 = xb[(2 * p + 1) << 10];
    xT[tid * 20 + p] = (unsigned)f2bf(v0) | ((unsigned)f2bf(v1) << 16);
  }
  __syncthreads();
  f32x4 acc[4][2];
  #pragma unroll
  for (int q = 0; q < 4; q++) {
    acc[q][0] = (f32x4){0.f, 0.f, 0.f, 0.f};
    acc[q][1] = (f32x4){0.f, 0.f, 0.f, 0.f};
  }
  int buf = 0;
  for (int kt = 0; kt < 7; kt++) {
    if (kt < 6) {                    // stage next chunk while MFMA on current
      const float* xc = xb + (((size_t)(kt + 1)) << 15);
      int cb = (kt + 1) * 32;
      #pragma unroll
      for (int p = 0; p < 16; p++) {
        int c = cb + 2 * p;
        float v0 = (c < 200) ? xc[(2 * p) << 10] : 0.f;
        float v1 = (c + 1 < 200) ? xc[(2 * p + 1) << 10] : 0.f;
        xT[(buf ^ 1) * 5120 + tid * 20 + p] = (unsigned)f2bf(v0) | ((unsigned)f2bf(v1) << 16);
      }
    }
    bf16x8 a0 = *reinterpret_cast<const bf16x8*>(&WfpL[(((kt << 1) + 0) * 64 + lane) << 3]);
    bf16x8 a1 = *reinterpret_cast<const bf16x8*>(&WfpL[(((kt << 1) + 1) * 64 + lane) << 3]);
    #pragma unroll
    for (int q = 0; q < 4; q++) {
      int px = ((w + (q << 2)) << 4) + li;
      bf16x8 bfr = *reinterpret_cast<const bf16x8*>(&xT[buf * 5120 + px * 20 + kg4]);
      acc[q][0] = MFMA16(a0, bfr, acc[q][0]);
      acc[q][1] = MFMA16(a1, bfr, acc[q][1]);
    }
    __syncthreads();
    buf ^= 1;
  }
  #pragma unroll
  for (int q = 0; q < 4; q++) {
    int px = ((w + (q << 2)) << 4) + li;
    size_t obase = (((size_t)b << 10) + l0 + px) << 5;
    #pragma unroll
    for (int m = 0; m < 2; m++) {
      f32x4 av = acc[q][m];
      ushort4 pk;
      pk.x = f2bf(fmaxf(fmaf(av[0], scv[m][0], sbv[m][0]), 0.f));
      pk.y = f2bf(fmaxf(fmaf(av[1], scv[m][1], sbv[m][1]), 0.f));
      pk.z = f2bf(fmaxf(fmaf(av[2], scv[m][2], sbv[m][2]), 0.f));
      pk.w = f2bf(fmaxf(fmaf(av[3], scv[m][3], sbv[m][3]), 0.f));
      *reinterpret_cast<ushort4*>(&p_bf[obase + m * 16 + ((lane >> 4) << 2)]) = pk;
    }
  }
}

// ---------------- K2: chunk-parallel mamba block: phases + intra-chunk scan -> (P,q,R,S) -
__global__ __launch_bounds__(1024, 4) void k_mamba(
    const unsigned short* __restrict__ p_bf,
    const unsigned short* __restrict__ Wfin,
    const unsigned short* __restrict__ Wfxp,
    const float* __restrict__ conv_w,    // (64,4)
    const float* __restrict__ conv_b,    // (64)
    const float* __restrict__ dt_w,      // (64,2)
    const float* __restrict__ dt_b,      // (64)
    const float* __restrict__ A_log,     // (64,16)
    float* __restrict__ pqrs,            // (128,16,64,16,4)
    float* __restrict__ au_g)            // (128,16,64)
{
  __shared__ __align__(16) char smem[65072];
  float* xm  = (float*)smem;                               // [67][68] f32 (xz rows; r=t+3)
  float* dlS = (float*)smem;                               // [64][68] alias (phase4+)
  unsigned short* ubS  = (unsigned short*)(smem + 18224);  // [64][72] bf16 u, t-major
  unsigned short* uTb  = (unsigned short*)(smem + 27440);  // [64][72] bf16 u, d-major
  unsigned short* duzP = (unsigned short*)(smem + 36656);  // [64][17][8] {du0..3, z0..3}
  float* bcT  = (float*)(smem + 54064);                    // [32][68]; cols 64..67 = dt01
  float* cwS  = (float*)(smem + 62768);                    // [64][4]
  float* cbS  = (float*)(smem + 63792);                    // [64]
  float* dtwS = (float*)(smem + 64048);                    // [64][2]
  float* dtbS = (float*)(smem + 64560);                    // [64]
  float* auS  = (float*)(smem + 64816);                    // [64]

  int b = blockIdx.x >> 4, ch = blockIdx.x & 15;
  int tid = threadIdx.x, lane = tid & 63, w = tid >> 6;
  int li = lane & 15, cig8 = (lane >> 4) << 3;

  if (tid < 256) cwS[tid] = conv_w[tid];
  else if (tid < 320) cbS[tid - 256] = conv_b[tid - 256];
  else if (tid < 448) dtwS[tid - 320] = dt_w[tid - 320];
  else if (tid < 512) dtbS[tid - 448] = dt_b[tid - 448];
  else if (tid < 576) auS[tid - 512] = 0.f;

  const unsigned short* pbf_b = p_bf + ((size_t)b << 15);

  // ---- phase1 (MFMA): xz = in_w @ tok ; x (rows -3..63) -> xm ; silu(z) -> duzP z-half --
  for (int j = w; j < 36; j += 16) {
    if (j < 20) {
      int ot = j / 5, tt = j % 5;
      int r = tt * 16 + li;
      int tg = (ch << 6) + r - 3;
      bf16x8 bfr = {0,0,0,0,0,0,0,0};
      if (r < 67 && tg >= 0)
        bfr = *reinterpret_cast<const bf16x8*>(pbf_b + ((size_t)tg << 5) + cig8);
      bf16x8 aW = *reinterpret_cast<const bf16x8*>(&Wfin[((ot << 6) + lane) << 3]);
      f32x4 acc = {0.f, 0.f, 0.f, 0.f};
      acc = MFMA16(aW, bfr, acc);
      if (r < 67)
        *reinterpret_cast<float4*>(&xm[r * 68 + (ot << 4) + ((lane >> 4) << 2)]) =
            make_float4(acc[0], acc[1], acc[2], acc[3]);
    } else {
      int jz = j - 20;
      int zot = jz >> 2, tt = jz & 3;
      int t = tt * 16 + li;
      int tg = (ch << 6) + t;
      bf16x8 bfr = *reinterpret_cast<const bf16x8*>(pbf_b + ((size_t)tg << 5) + cig8);
      bf16x8 aW = *reinterpret_cast<const bf16x8*>(&Wfin[(((4 + zot) << 6) + lane) << 3]);
      f32x4 acc = {0.f, 0.f, 0.f, 0.f};
      acc = MFMA16(aW, bfr, acc);
      int dzb = (zot << 4) + ((lane >> 4) << 2);
      int toff = ((t >> 2) << 3) + 4 + (t & 3);
      #pragma unroll
      for (int q = 0; q < 4; q++)
        duzP[(dzb + q) * 136 + toff] = f2bf(silu_(acc[q]));
    }
  }
  __syncthreads();                        // B: xm, z, weights ready
  // ---- phase2: causal dwconv(4) + silu -> ubS, uTb ; au partial -> auS -----------------
  {
    int d2 = tid & 63, oct = tid >> 6;
    int t0 = oct << 2;
    float4 cw4 = *reinterpret_cast<const float4*>(&cwS[d2 << 2]);
    float cb1 = cbS[d2];
    float x0 = xm[t0 * 68 + d2], x1 = xm[(t0 + 1) * 68 + d2], x2 = xm[(t0 + 2) * 68 + d2];
    uint2 zz2 = *reinterpret_cast<const uint2*>(&duzP[d2 * 136 + (oct << 3) + 4]);
    float zf[4];
    bf2x(zz2.x, zf[0], zf[1]); bf2x(zz2.y, zf[2], zf[3]);
    unsigned short up[4];
    float aup = 0.f;
    #pragma unroll
    for (int s = 0; s < 4; s++) {
      int t = t0 + s;
      float x3 = xm[(t + 3) * 68 + d2];
      float a = cb1;
      a = fmaf(cw4.x, x0, a); a = fmaf(cw4.y, x1, a);
      a = fmaf(cw4.z, x2, a); a = fmaf(cw4.w, x3, a);
      float uu = silu_(a);
      unsigned short ub_ = f2bf(uu);
      ubS[t * 72 + d2] = ub_;
      up[s] = ub_;
      aup = fmaf(uu, zf[s], aup);
      x0 = x1; x1 = x2; x2 = x3;
    }
    uint2 pk;
    pk.x = (unsigned)up[0] | ((unsigned)up[1] << 16);
    pk.y = (unsigned)up[2] | ((unsigned)up[3] << 16);
    *reinterpret_cast<uint2*>(&uTb[d2 * 72 + t0]) = pk;
    atomicAdd(&auS[d2], aup);
  }
  __syncthreads();                        // C: u ready
  // ---- phase3 (MFMA): xdbl = xp_w @ u ; dt -> bcT pad, B/C -> bcT ----------------------
  if (w < 12) {
    int ot = w >> 2, tt = w & 3;
    int t = tt * 16 + li;
    const unsigned short* ub = &ubS[t * 72];
    bf16x8 b0 = *reinterpret_cast<const bf16x8*>(ub + cig8);
    bf16x8 b1 = *reinterpret_cast<const bf16x8*>(ub + 32 + cig8);
    bf16x8 a0 = *reinterpret_cast<const bf16x8*>(&Wfxp[(((ot << 1) + 0) * 64 + lane) << 3]);
    bf16x8 a1 = *reinterpret_cast<const bf16x8*>(&Wfxp[(((ot << 1) + 1) * 64 + lane) << 3]);
    f32x4 acc = {0.f, 0.f, 0.f, 0.f};
    acc = MFMA16(a0, b0, acc);
    acc = MFMA16(a1, b1, acc);
    int jb = (ot << 4) + ((lane >> 4) << 2);
    #pragma unroll
    for (int q = 0; q < 4; q++) {
      int jj = jb + q;
      if (jj < 2) bcT[(t & 31) * 68 + 64 + (jj << 1) + (t >> 5)] = acc[q];
      else if (jj < 34) bcT[(jj - 2) * 68 + t] = acc[q];
    }
  }
  __syncthreads();                        // D: bcT (incl dt01) ready
  // ---- phase4: delta = softplus(..) -> dlS ; du = delta*u -> duzP du-half --------------
  // lane->dg mapping stride-1 (l15 + 16q) => 2-way banks (was stride-4 => 8-way)
  {
    int t = tid >> 4, l15 = tid & 15;
    int tr = t & 31, th = t >> 5;
    float d0 = bcT[tr * 68 + 64 + th];
    float d1 = bcT[tr * 68 + 66 + th];
    int toff = ((t >> 2) << 3) + (t & 3);
    #pragma unroll
    for (int q = 0; q < 4; q++) {
      int dg = l15 + (q << 4);
      float pre = fmaf(d0, dtwS[dg << 1], fmaf(d1, dtwS[(dg << 1) + 1], dtbS[dg]));
      float dl_ = (pre > 20.f) ? pre : __logf(1.f + __expf(pre));
      dlS[dg * 68 + t] = dl_;
      float uf = bflo(uTb[dg * 72 + t]);
      duzP[dg * 136 + toff] = f2bf(dl_ * uf);
    }
  }
  __syncthreads();                        // E: dlS, duzP ready
  // ---- intra-chunk scan: h_out = P h_in + q ; y = R h_in + S ---------------------------
  {
    int sd = tid >> 4, sn = tid & 15;
    float Areg2 = -__expf(A_log[(sd << 4) + sn]) * 1.44269504f;
    float P = 1.f, qq = 0.f, R = 0.f, S = 0.f;
    const float* dr = &dlS[sd * 68];
    const unsigned short* dz = &duzP[sd * 136];
    const float* Br = &bcT[sn * 68];
    const float* Cr = &bcT[(16 + sn) * 68];
    for (int g = 0; g < 16; g++) {
      float4 dv = *reinterpret_cast<const float4*>(dr + (g << 2));
      uint4 duz = *reinterpret_cast<const uint4*>(dz + (g << 3));
      float4 Bv = *reinterpret_cast<const float4*>(Br + (g << 2));
      float4 Cv = *reinterpret_cast<const float4*>(Cr + (g << 2));
      float du0, du1, du2, du3, z0, z1, z2, z3;
      bf2x(duz.x, du0, du1); bf2x(duz.y, du2, du3);
      bf2x(duz.z, z0, z1);  bf2x(duz.w, z2, z3);
      float e0 = fastexp2(dv.x * Areg2), e1 = fastexp2(dv.y * Areg2);
      float e2 = fastexp2(dv.z * Areg2), e3 = fastexp2(dv.w * Areg2);
      float c0 = Cv.x * z0, c1 = Cv.y * z1, c2 = Cv.z * z2, c3 = Cv.w * z3;
      P = e0 * P; qq = fmaf(e0, qq, du0 * Bv.x); R = fmaf(c0, P, R); S = fmaf(c0, qq, S);
      P = e1 * P; qq = fmaf(e1, qq, du1 * Bv.y); R = fmaf(c1, P, R); S = fmaf(c1, qq, S);
      P = e2 * P; qq = fmaf(e2, qq, du2 * Bv.z); R = fmaf(c2, P, R); S = fmaf(c2, qq, S);
      P = e3 * P; qq = fmaf(e3, qq, du3 * Bv.w); R = fmaf(c3, P, R); S = fmaf(c3, qq, S);
    }
    size_t idx = ((((size_t)b << 4) + ch) << 10) + (sd << 4) + sn;
    *reinterpret_cast<float4*>(pqrs + (idx << 2)) = make_float4(P, qq, R, S);
    if (sn == 0) au_g[((((size_t)b << 4) + ch) << 6) + sd] = auS[sd];
  }
}

// ---------------- K3a: conv1 3x3 VALID (32->32) + BN1 + ReLU, MFMA, -> c1_bf -------------
__global__ __launch_bounds__(256) void k_conv1m(
    const unsigned short* __restrict__ p_bf, const unsigned short* __restrict__ Wf1,
    const float* __restrict__ cbias,
    const float* __restrict__ g, const float* __restrict__ be,
    const float* __restrict__ mm, const float* __restrict__ vv,
    unsigned short* __restrict__ c1_bf)
{
  __shared__ __align__(16) unsigned short inS[8 * 32 * 40];  // [row][x][ci pad40]
  int b = blockIdx.x / 5, s = blockIdx.x % 5;
  int y0 = s * 6;
  int tid = threadIdx.x, lane = tid & 63, w = tid >> 6;
  int li = lane & 15, cig8 = (lane >> 4) << 3;
  for (int uu = tid; uu < 1024; uu += 256) {
    int r = uu >> 7, rem = uu & 127;
    uint4 v = *reinterpret_cast<const uint4*>(
        &p_bf[((((size_t)b << 10) + (y0 + r) * 32) << 5) + rem * 8]);
    int xx = rem >> 2, cg = rem & 3;
    *reinterpret_cast<uint4*>(&inS[(r * 32 + xx) * 40 + cg * 8]) = v;
  }
  bf16x8 aw[9][2];
  #pragma unroll
  for (int t = 0; t < 9; t++)
    #pragma unroll
    for (int m = 0; m < 2; m++)
      aw[t][m] = *reinterpret_cast<const bf16x8*>(&Wf1[(((t << 1) + m) * 64 + lane) * 8]);
  float scv[2][4], sbv[2][4];
  #pragma unroll
  for (int m = 0; m < 2; m++)
    #pragma unroll
    for (int j = 0; j < 4; j++) {
      int co = m * 16 + ((lane >> 4) << 2) + j;
      float sc = g[co] * rsqrtf(vv[co] + 1e-5f);
      scv[m][j] = sc;
      sbv[m][j] = fmaf(cbias[co] - mm[co], sc, be[co]);
    }
  __syncthreads();
  #pragma unroll
  for (int q = 0; q < 3; q++) {
    int pf = w + q * 4;
    int p = pf * 16 + li;
    int pv = (p < 180) ? p : 0;
    int ry = pv / 30, rx = pv % 30;
    f32x4 a0 = {0.f, 0.f, 0.f, 0.f}, a1 = {0.f, 0.f, 0.f, 0.f};
    #pragma unroll
    for (int t = 0; t < 9; t++) {
      int dy = t / 3, dx = t % 3;
      bf16x8 bfr = *reinterpret_cast<const bf16x8*>(
          &inS[((ry + dy) * 32 + rx + dx) * 40 + cig8]);
      a0 = MFMA16(aw[t][0], bfr, a0);
      a1 = MFMA16(aw[t][1], bfr, a1);
    }
    if (p < 180) {
      size_t obase = ((size_t)b * 900 + (size_t)(y0 + ry) * 30 + rx) << 5;
      #pragma unroll
      for (int m = 0; m < 2; m++) {
        f32x4 av = m ? a1 : a0;
        ushort4 pk;
        pk.x = f2bf(fmaxf(fmaf(av[0], scv[m][0], sbv[m][0]), 0.f));
        pk.y = f2bf(fmaxf(fmaf(av[1], scv[m][1], sbv[m][1]), 0.f));
        pk.z = f2bf(fmaxf(fmaf(av[2], scv[m][2], sbv[m][2]), 0.f));
        pk.w = f2bf(fmaxf(fmaf(av[3], scv[m][3], sbv[m][3]), 0.f));
        *reinterpret_cast<ushort4*>(&c1_bf[obase + m * 16 + ((lane >> 4) << 2)]) = pk;
      }
    }
  }
}

// ---------------- K3b: FUSED back: conv2 blocks (0..895) || comb blocks (896..1407) ------
__global__ __launch_bounds__(256) void k_back(
    const unsigned short* __restrict__ c1_bf, const unsigned short* __restrict__ Wf2,
    const float* __restrict__ cb2,
    const float* __restrict__ g, const float* __restrict__ be,
    const float* __restrict__ mm, const float* __restrict__ vv,
    const float* __restrict__ pqrs, const float* __restrict__ au_g,
    const float* __restrict__ Dp,
    float* __restrict__ cnn_sum, float* __restrict__ ybar)
{
  __shared__ __align__(16) unsigned short inS[6 * 30 * 40];
  int tid = threadIdx.x;
  if (blockIdx.x >= 896) {    // ---- comb branch: block = (b, 16-d quarter) ----
    int cb = blockIdx.x - 896;
    int b = cb >> 2, qq4 = cb & 3;
    int sd = (qq4 << 4) + (tid >> 4), sn = tid & 15;
    float4 pq[16];
    #pragma unroll
    for (int c = 0; c < 16; c++) {
      size_t idx = ((((size_t)b << 4) + c) << 10) + (sd << 4) + sn;
      pq[c] = *reinterpret_cast<const float4*>(pqrs + (idx << 2));
    }
    float h = 0.f, y = 0.f;
    #pragma unroll
    for (int c = 0; c < 16; c++) {
      y = fmaf(pq[c].z, h, y + pq[c].w);
      h = fmaf(pq[c].x, h, pq[c].y);
    }
    float val = y + Dp[sd] * au_g[((((size_t)b << 4) + sn) << 6) + sd];
    val += __shfl_xor(val, 1); val += __shfl_xor(val, 2);
    val += __shfl_xor(val, 4); val += __shfl_xor(val, 8);
    if (sn == 0) ybar[(b << 6) + sd] = val * (1.f / 1024.f);
    return;
  }
  // ---- conv2 branch ----
  int b = blockIdx.x / 7, s = blockIdx.x % 7;
  int y0 = s * 4;
  int lane = tid & 63, w = tid >> 6;
  int li = lane & 15, cig8 = (lane >> 4) << 3;
  for (int uu = tid; uu < 720; uu += 256) {
    int r = uu / 120, rem = uu % 120;
    uint4 v = *reinterpret_cast<const uint4*>(
        &c1_bf[(((size_t)b * 900 + (size_t)(y0 + r) * 30) << 5) + rem * 8]);
    int xx = rem >> 2, cg = rem & 3;
    *reinterpret_cast<uint4*>(&inS[(r * 30 + xx) * 40 + cg * 8]) = v;
  }
  bf16x8 aw[9][2];
  #pragma unroll
  for (int t = 0; t < 9; t++)
    #pragma unroll
    for (int m = 0; m < 2; m++)
      aw[t][m] = *reinterpret_cast<const bf16x8*>(&Wf2[(((t << 3) + (w << 1) + m) * 64 + lane) * 8]);
  float scv[2][4], sbv[2][4];
  float psum[2][4] = {{0.f,0.f,0.f,0.f},{0.f,0.f,0.f,0.f}};
  #pragma unroll
  for (int m = 0; m < 2; m++)
    #pragma unroll
    for (int j = 0; j < 4; j++) {
      int co = (w << 5) + m * 16 + ((lane >> 4) << 2) + j;
      float sc = g[co] * rsqrtf(vv[co] + 1e-5f);
      scv[m][j] = sc;
      sbv[m][j] = fmaf(cb2[co] - mm[co], sc, be[co]);
    }
  __syncthreads();
  #pragma unroll
  for (int pf = 0; pf < 7; pf++) {
    int p = pf * 16 + li;
    int ry = p / 28, rx = p % 28;
    f32x4 a0 = {0.f, 0.f, 0.f, 0.f}, a1 = {0.f, 0.f, 0.f, 0.f};
    #pragma unroll
    for (int t = 0; t < 9; t++) {
      int dy = t / 3, dx = t % 3;
      bf16x8 bfr = *reinterpret_cast<const bf16x8*>(
          &inS[((ry + dy) * 30 + rx + dx) * 40 + cig8]);
      a0 = MFMA16(aw[t][0], bfr, a0);
      a1 = MFMA16(aw[t][1], bfr, a1);
    }
    #pragma unroll
    for (int j = 0; j < 4; j++) {
      psum[0][j] += fmaxf(fmaf(a0[j], scv[0][j], sbv[0][j]), 0.f);
      psum[1][j] += fmaxf(fmaf(a1[j], scv[1][j], sbv[1][j]), 0.f);
    }
  }
  #pragma unroll
  for (int m = 0; m < 2; m++)
    #pragma unroll
    for (int j = 0; j < 4; j++) {
      float v = psum[m][j];
      v += __shfl_xor(v, 1); v += __shfl_xor(v, 2);
      v += __shfl_xor(v, 4); v += __shfl_xor(v, 8);
      if (li == 0) {
        int co = (w << 5) + m * 16 + ((lane >> 4) << 2) + j;
        atomicAdd(&cnn_sum[((size_t)b << 7) + co], v);
      }
    }
}

// ---------------- K4: out = ybar @ W2^T + fc_b + cnn_sum/784 ----------------
__global__ __launch_bounds__(256) void k_final(
    const float* __restrict__ ybar, const float* __restrict__ W2,
    const float* __restrict__ fc_b, const float* __restrict__ cnn_sum,
    float* __restrict__ out)
{
  int i = blockIdx.x * 256 + threadIdx.x;   // 16384
  int b = i >> 7, f = i & 127;
  float a = 0.f;
  #pragma unroll
  for (int d2 = 0; d2 < 64; d2++) a = fmaf(ybar[(b << 6) + d2], W2[(f << 6) + d2], a);
  out[i] = a + fc_b[f] + cnn_sum[i] * (1.f / 784.f);
}

extern "C" void kernel_launch(void* const* d_in, const int* in_sizes, int n_in,
                              void* d_out, int out_size, void* d_ws, size_t ws_size,
                              hipStream_t stream) {
  (void)in_sizes; (void)n_in; (void)out_size; (void)ws_size;
  const float* x         = (const float*)d_in[0];
  const float* proj_w    = (const float*)d_in[1];
  const float* proj_b    = (const float*)d_in[2];
  const float* bn0_g     = (const float*)d_in[3];
  const float* bn0_b     = (const float*)d_in[4];
  const float* bn0_m     = (const float*)d_in[5];
  const float* bn0_v     = (const float*)d_in[6];
  const float* in_proj_w = (const float*)d_in[7];
  const float* conv_w    = (const float*)d_in[8];
  const float* conv_b    = (const float*)d_in[9];
  const float* x_proj_w  = (const float*)d_in[10];
  const float* dt_w      = (const float*)d_in[11];
  const float* dt_b      = (const float*)d_in[12];
  const float* A_log     = (const float*)d_in[13];
  const float* Dp        = (const float*)d_in[14];
  const float* out_proj_w= (const float*)d_in[15];
  const float* fc_w      = (const float*)d_in[16];
  const float* fc_b      = (const float*)d_in[17];
  const float* c1_w      = (const float*)d_in[18];
  const float* c1_b      = (const float*)d_in[19];
  const float* bn1_g     = (const float*)d_in[20];
  const float* bn1_b     = (const float*)d_in[21];
  const float* bn1_m     = (const float*)d_in[22];
  const float* bn1_v     = (const float*)d_in[23];
  const float* c2_w      = (const float*)d_in[24];
  const float* c2_b      = (const float*)d_in[25];
  const float* bn2_g     = (const float*)d_in[26];
  const float* bn2_b     = (const float*)d_in[27];
  const float* bn2_m     = (const float*)d_in[28];
  const float* bn2_v     = (const float*)d_in[29];
  float* out = (float*)d_out;
  float* ws  = (float*)d_ws;
  // workspace layout (float slots); ~50 MB
  float* ybar    = ws;                                        // 8192
  float* cnn_sum = ws + 8192;                                 // 16384
  float* W2      = ws + 24576;                                // 8192
  float* pqrs    = ws + 32768;                                // 8388608
  float* au_g    = ws + 8421376;                              // 131072
  unsigned short* p_bf  = (unsigned short*)(ws + 8552448);    // 4194304 bf16
  unsigned short* c1_bf = (unsigned short*)(ws + 10649600);   // 3686400 bf16
  unsigned short* Wf1   = (unsigned short*)(ws + 12492800);   // 9216 bf16
  unsigned short* Wf2   = (unsigned short*)(ws + 12497408);   // 36864 bf16
  unsigned short* Wfin  = (unsigned short*)(ws + 12515840);   // 4096 bf16
  unsigned short* Wfxp  = (unsigned short*)(ws + 12517888);   // 3072 bf16

  k_front<<<dim3(816), dim3(256), 0, stream>>>(x, proj_w, proj_b, bn0_g, bn0_b, bn0_m, bn0_v,
                                               c1_w, c2_w, fc_w, out_proj_w, in_proj_w, x_proj_w,
                                               p_bf, Wf1, Wf2, Wfin, Wfxp, W2, cnn_sum);
  k_mamba<<<dim3(2048), dim3(1024), 0, stream>>>(p_bf, Wfin, Wfxp, conv_w, conv_b, dt_w, dt_b,
                                                 A_log, pqrs, au_g);
  k_conv1m<<<dim3(640), dim3(256), 0, stream>>>(p_bf, Wf1, c1_b, bn1_g, bn1_b, bn1_m, bn1_v, c1_bf);
  k_back<<<dim3(1408), dim3(256), 0, stream>>>(c1_bf, Wf2, c2_b, bn2_g, bn2_b, bn2_m, bn2_v,
                                               pqrs, au_g, Dp, cnn_sum, ybar);
  k_final<<<dim3(64), dim3(256), 0, stream>>>(ybar, W2, fc_b, cnn_sum, out);
}